// Round 3
// baseline (18379.443 us; speedup 1.0000x reference)
//
#include <hip/hip_runtime.h>
#include <math.h>

// Problem constants (match reference file)
#define BATCH 4
#define NPTS 16384
#define M 4096          // centers per cloud = RATIO * NPTS
#define MAX_NB 64
#define R2F 0.0625f     // R*R = 0.25*0.25 (exactly representable)

// FPS split: KS blocks per cloud, each owning NPTS/KS points.
#define KS 4
#define FPS_T 512                 // threads per FPS block
#define WPB (FPS_T / 64)          // waves per block = 8
#define NW (KS * WPB)             // wave-slots per cloud = 32
#define PPB (NPTS / KS)           // points per block = 4096
#define PPT (PPB / FPS_T)         // points per thread = 8

// ---------------------------------------------------------------------------
// Semantics (B): XLA-fused scan-body rounding (verified bit-exact in R3).
// ---------------------------------------------------------------------------
__device__ __forceinline__ float dist2_fma(
    float a0, float a1, float a2, float a3, float a4, float a5,
    float b0, float b1, float b2, float b3, float b4, float b5) {
  float d0 = a0 - b0;
  float s = __builtin_fmaf(d0, d0, 0.0f);
  float d1 = a1 - b1; s = __builtin_fmaf(d1, d1, s);
  float d2 = a2 - b2; s = __builtin_fmaf(d2, d2, s);
  float d3 = a3 - b3; s = __builtin_fmaf(d3, d3, s);
  float d4 = a4 - b4; s = __builtin_fmaf(d4, d4, s);
  float d5 = a5 - b5; s = __builtin_fmaf(d5, d5, s);
  return s;
}

// Semantics (A): op-by-op numpy/jnp rounding for the neighbor phase.
__device__ __forceinline__ float dist2_seq(
    float a0, float a1, float a2, float a3, float a4, float a5,
    float b0, float b1, float b2, float b3, float b4, float b5) {
#pragma clang fp contract(off)
  float d0 = a0 - b0; float s = d0 * d0;
  float d1 = a1 - b1; s = s + d1 * d1;
  float d2 = a2 - b2; s = s + d2 * d2;
  float d3 = a3 - b3; s = s + d3 * d3;
  float d4 = a4 - b4; s = s + d4 * d4;
  float d5 = a5 - b5; s = s + d5 * d5;
  return s;
}

// ---------------------------------------------------------------------------
// Kernel 1: FPS, KS=4 blocks per cloud, BARRIER-FREE pick loop.
//
// R2 POST-MORTEM: splitting compute 4x gained nothing — the pick loop is a
// serial LATENCY chain. The intra-block stage (wave shfl -> LDS -> 2x
// __syncthreads -> serialized wave0 scan) plus the cross-block store->poll
// round trip cost ~5100 cy/pick, hiding the 640-cy compute entirely.
//
// R3 RESTRUCTURE: flatten the reduction to ONE level. Each of the cloud's
// NW=32 waves publishes its own wave-winner key straight to a global slot;
// every wave polls all 32 slots (lane L reads slot L&31 — agent-scope
// relaxed atomic loads compile to cache-bypassing plain loads, no RMW) and
// reduces with a 5-step shfl_xor umax. No __syncthreads, no LDS, a single
// global round trip per pick.
//
//   key = [57:46]=iter_tag(k+1) | [45:14]=float_bits(bestv) | [13:0]=16383-idx
//
// umax over keys == argmax with tie -> smallest index (bestv >= 0 so float
// bits are order-preserving; inverted idx turns max into min-index on ties).
// Max over keys with unique index bits is associative/commutative, so the
// flattened reduction order is bit-identical to R2's two-level one.
//
// Lap race: slot sets are double-buffered by iteration parity (set = k&1),
// same proof as R2 with waves as the agents: a wave rewrites set s at k+2
// only after passing its k+1 poll, which requires every wave to have
// published tag k+2, which happens only AFTER that wave finished its
// iteration-k poll of set s. Publish-before-poll => no deadlock. All
// communicated state lives in one 64-bit word => relaxed is sufficient.
// Ordering is enforced by data dependence: the k+2 key depends on mind[]
// updated with the k+1 pick, which comes from the k+1 poll result.
// ---------------------------------------------------------------------------
__global__
__attribute__((amdgpu_flat_work_group_size(FPS_T, FPS_T)))
__attribute__((amdgpu_waves_per_eu(2, 2)))
void fps_kernel(
    const float* __restrict__ x, const float* __restrict__ pos,
    float* __restrict__ out, unsigned long long* __restrict__ slots) {
  const int b = blockIdx.x & (BATCH - 1);  // cloud
  const int sblk = blockIdx.x >> 2;        // sub-block within cloud (0..KS-1)
  const int t = threadIdx.x;
  const int w = t >> 6;                    // wave within block
  const int lane = t & 63;
  const int gw = sblk * WPB + w;           // wave id within cloud (0..NW-1)

  const float* xb = x + (size_t)b * NPTS * 3;
  const float* pb = pos + (size_t)b * NPTS * 3;

  float* out_pos = out + (size_t)BATCH * M * 3;              // second output
  int* idx_stash = (int*)(out + (size_t)2 * BATCH * M * 3);  // batch region

  const int pbase = sblk * PPB;  // this block's point range

  // My 8 points' 6-D coords + mind, all registers (56 f32 -> clean VGPR fit).
  float c0[PPT], c1[PPT], c2[PPT], c3[PPT], c4[PPT], c5[PPT], mind[PPT];
#pragma unroll
  for (int j = 0; j < PPT; ++j) {
    const int p = pbase + j * FPS_T + t;
    c0[j] = xb[3 * p + 0];
    c1[j] = xb[3 * p + 1];
    c2[j] = xb[3 * p + 2];
    c3[j] = pb[3 * p + 0];
    c4[j] = pb[3 * p + 1];
    c5[j] = pb[3 * p + 2];
    mind[j] = INFINITY;  // minimum(inf, d) == d on the first pick
  }

  int g = 0;  // current pick (wave-uniform; scalarized via readfirstlane)
  for (int k = 0; k < M; ++k) {
    // g is wave-uniform -> scalar center loads (L2-resident).
    const float fx0 = xb[3 * g + 0];
    const float fx1 = xb[3 * g + 1];
    const float fx2 = xb[3 * g + 2];
    const float fx3 = pb[3 * g + 0];
    const float fx4 = pb[3 * g + 1];
    const float fx5 = pb[3 * g + 2];

    if (sblk == 0 && t == 0) {
      idx_stash[b * M + k] = g;                    // for kernel 2
      out_pos[(size_t)(b * M + k) * 3 + 0] = fx3;  // pos[idx_g] (exact copy)
      out_pos[(size_t)(b * M + k) * 3 + 1] = fx4;
      out_pos[(size_t)(b * M + k) * 3 + 2] = fx5;
    }
    if (k == M - 1) break;  // last pick needs no further update/argmax

    // Min-update + per-thread (max, first-j). j ascending => p ascending, so
    // strict > keeps the earliest original index within this thread.
    float bestv = -1.0f;  // minds are >= 0
    int bestj = 0;
#pragma unroll
    for (int j = 0; j < PPT; ++j) {
      const float d2 = dist2_fma(c0[j], c1[j], c2[j], c3[j], c4[j], c5[j],
                                 fx0, fx1, fx2, fx3, fx4, fx5);
      const float nm = fminf(mind[j], d2);  // == jnp.minimum (no NaNs)
      mind[j] = nm;
      if (nm > bestv) {
        bestv = nm;
        bestj = j;
      }
    }
    int besti = pbase + bestj * FPS_T + t;  // cloud-local point index

    // Wave-level argmax reduce, tie -> smaller index.
#pragma unroll
    for (int off = 32; off > 0; off >>= 1) {
      const float ov = __shfl_xor(bestv, off, 64);
      const int oi = __shfl_xor(besti, off, 64);
      if (ov > bestv || (ov == bestv && oi < besti)) {
        bestv = ov;
        besti = oi;
      }
    }

    // Publish this wave's key; poll all NW wave-keys; flat umax reduce.
    const unsigned long long key =
        ((unsigned long long)(unsigned)(k + 1) << 46) |
        ((unsigned long long)__float_as_uint(bestv) << 14) |
        (unsigned long long)(unsigned)(16383 - besti);
    unsigned long long* set =
        slots + (size_t)(((k & 1) * BATCH + b) * NW);
    if (lane == 0) {
      __hip_atomic_store(&set[gw], key, __ATOMIC_RELAXED,
                         __HIP_MEMORY_SCOPE_AGENT);
    }
    unsigned long long other;
    {
      const unsigned long long want = (unsigned long long)(unsigned)(k + 1);
      unsigned long long* myslot = &set[lane & (NW - 1)];
      do {
        other = __hip_atomic_load(myslot, __ATOMIC_RELAXED,
                                  __HIP_MEMORY_SCOPE_AGENT);
      } while ((other >> 46) < want);
    }
#pragma unroll
    for (int off = 1; off < NW; off <<= 1) {
      const unsigned long long o = __shfl_xor(other, off, 64);
      if (o > other) other = o;
    }
    g = __builtin_amdgcn_readfirstlane(16383 - (int)(other & 0x3FFFull));
  }
}

// ---------------------------------------------------------------------------
// Kernel 2: radius-neighbor capped mean (passed R3, ~0.15 ms). Unchanged.
// ---------------------------------------------------------------------------
#define K2_T 256
__global__ __launch_bounds__(K2_T, 4) void nbr_kernel(
    const float* __restrict__ x, const float* __restrict__ pos,
    float* __restrict__ out) {
  const int lane = threadIdx.x & 63;
  const int w = threadIdx.x >> 6;
  const int cbase = blockIdx.x * 16 + w * 4;  // 4 centers per wave

  const int* idx_stash = (const int*)(out + (size_t)2 * BATCH * M * 3);
  float* out_x = out;
  float* out_batch = out + (size_t)2 * BATCH * M * 3;

  const int b = cbase / M;  // all 16 centers of a block share a cloud
  const float* xb = x + (size_t)b * NPTS * 3;
  const float* pb = pos + (size_t)b * NPTS * 3;

  float cc0[4], cc1[4], cc2[4], cc3[4], cc4[4], cc5[4];
#pragma unroll
  for (int i = 0; i < 4; ++i) {
    const int c = idx_stash[cbase + i];  // local index within cloud
    cc0[i] = xb[3 * c + 0];
    cc1[i] = xb[3 * c + 1];
    cc2[i] = xb[3 * c + 2];
    cc3[i] = pb[3 * c + 0];
    cc4[i] = pb[3 * c + 1];
    cc5[i] = pb[3 * c + 2];
  }

  float s0[4] = {0, 0, 0, 0}, s1[4] = {0, 0, 0, 0}, s2[4] = {0, 0, 0, 0};
  int cnt[4] = {0, 0, 0, 0};

  for (int p = lane; p < NPTS; p += 64) {
    const float x0 = xb[3 * p + 0];
    const float x1 = xb[3 * p + 1];
    const float x2 = xb[3 * p + 2];
    const float q0 = pb[3 * p + 0];
    const float q1 = pb[3 * p + 1];
    const float q2 = pb[3 * p + 2];
#pragma unroll
    for (int i = 0; i < 4; ++i) {
      const float d2 = dist2_seq(cc0[i], cc1[i], cc2[i], cc3[i], cc4[i],
                                 cc5[i], x0, x1, x2, q0, q1, q2);
      if (d2 <= R2F) {
        cnt[i] += 1;
        s0[i] += x0;
        s1[i] += x1;
        s2[i] += x2;
      }
    }
  }

#pragma unroll
  for (int i = 0; i < 4; ++i) {
#pragma unroll
    for (int off = 32; off > 0; off >>= 1) {
      s0[i] += __shfl_xor(s0[i], off, 64);
      s1[i] += __shfl_xor(s1[i], off, 64);
      s2[i] += __shfl_xor(s2[i], off, 64);
      cnt[i] += __shfl_xor(cnt[i], off, 64);
    }
  }

#pragma unroll
  for (int i = 0; i < 4; ++i) {
    const int total = cnt[i];
    float m0, m1, m2;
    if (total <= MAX_NB) {
      const float denom = (float)total;  // >= 1 (self is always in range)
      m0 = s0[i] / denom;
      m1 = s1[i] / denom;
      m2 = s2[i] / denom;
    } else {
      // Exact first-64-by-index fallback (wave-uniform branch, rare).
      const int base = lane * (NPTS / 64);
      int lc = 0;
      for (int p = base; p < base + NPTS / 64; ++p) {
        const float d2 =
            dist2_seq(cc0[i], cc1[i], cc2[i], cc3[i], cc4[i], cc5[i],
                      xb[3 * p + 0], xb[3 * p + 1], xb[3 * p + 2],
                      pb[3 * p + 0], pb[3 * p + 1], pb[3 * p + 2]);
        if (d2 <= R2F) lc += 1;
      }
      int pre = 0;
      for (int l = 0; l < 64; ++l) {
        const int c = __shfl(lc, l, 64);
        if (l < lane) pre += c;
      }
      float t0 = 0, t1 = 0, t2 = 0;
      int r = pre;
      for (int p = base; p < base + NPTS / 64; ++p) {
        const float x0 = xb[3 * p + 0], x1 = xb[3 * p + 1],
                    x2 = xb[3 * p + 2];
        const float d2 =
            dist2_seq(cc0[i], cc1[i], cc2[i], cc3[i], cc4[i], cc5[i], x0, x1,
                      x2, pb[3 * p + 0], pb[3 * p + 1], pb[3 * p + 2]);
        if (d2 <= R2F) {
          if (r < MAX_NB) {
            t0 += x0;
            t1 += x1;
            t2 += x2;
          }
          r += 1;
        }
      }
#pragma unroll
      for (int off = 32; off > 0; off >>= 1) {
        t0 += __shfl_xor(t0, off, 64);
        t1 += __shfl_xor(t1, off, 64);
        t2 += __shfl_xor(t2, off, 64);
      }
      m0 = t0 / 64.0f;
      m1 = t1 / 64.0f;
      m2 = t2 / 64.0f;
    }
    if (lane == i) {
      const int gc = cbase + i;
      out_x[(size_t)gc * 3 + 0] = m0;
      out_x[(size_t)gc * 3 + 1] = m1;
      out_x[(size_t)gc * 3 + 2] = m2;
      out_batch[gc] = (float)b;  // batch ids as float in the float32 buffer
    }
  }
}

extern "C" void kernel_launch(void* const* d_in, const int* in_sizes, int n_in,
                              void* d_out, int out_size, void* d_ws,
                              size_t ws_size, hipStream_t stream) {
  (void)in_sizes;
  (void)n_in;
  (void)out_size;
  const float* x = (const float*)d_in[0];
  const float* pos = (const float*)d_in[1];
  // d_in[2] (batch) is implied by the contiguous equal-size layout.
  float* out = (float*)d_out;

  // Cross-wave exchange slots, double-buffered by iteration parity:
  // [2][BATCH][NW] u64 = 2 KiB. Prefer the workspace; fall back to the head
  // of out_x (fully overwritten later by nbr_kernel; never read by fps).
  const size_t slot_bytes =
      (size_t)2 * BATCH * NW * sizeof(unsigned long long);
  unsigned long long* slots = (ws_size >= slot_bytes)
                                  ? (unsigned long long*)d_ws
                                  : (unsigned long long*)d_out;
  // Must clear every launch: stale tags from a previous run would satisfy
  // the tag-poll early and corrupt picks on graph replay.
  hipMemsetAsync(slots, 0, slot_bytes, stream);

  fps_kernel<<<BATCH * KS, FPS_T, 0, stream>>>(x, pos, out, slots);
  nbr_kernel<<<(BATCH * M) / 16, K2_T, 0, stream>>>(x, pos, out);
}

// Round 4
// 11026.727 us; speedup vs baseline: 1.6668x; 1.6668x over previous
//
#include <hip/hip_runtime.h>
#include <math.h>

// Problem constants (match reference file)
#define BATCH 4
#define NPTS 16384
#define M 4096          // centers per cloud = RATIO * NPTS
#define MAX_NB 64
#define R2F 0.0625f     // R*R = 0.25*0.25 (exactly representable)

// FPS split: KS blocks per cloud, each owning NPTS/KS points.
#define KS 4
#define FPS_T 512                 // threads per FPS block
#define WPB (FPS_T / 64)          // waves per block = 8
#define NW (KS * WPB)             // wave-slots per cloud = 32
#define PPB (NPTS / KS)           // points per block = 4096
#define PPT (PPB / FPS_T)         // points per thread = 8

// ---------------------------------------------------------------------------
// Semantics (B): XLA-fused scan-body rounding (verified bit-exact in R3).
// ---------------------------------------------------------------------------
__device__ __forceinline__ float dist2_fma(
    float a0, float a1, float a2, float a3, float a4, float a5,
    float b0, float b1, float b2, float b3, float b4, float b5) {
  float d0 = a0 - b0;
  float s = __builtin_fmaf(d0, d0, 0.0f);
  float d1 = a1 - b1; s = __builtin_fmaf(d1, d1, s);
  float d2 = a2 - b2; s = __builtin_fmaf(d2, d2, s);
  float d3 = a3 - b3; s = __builtin_fmaf(d3, d3, s);
  float d4 = a4 - b4; s = __builtin_fmaf(d4, d4, s);
  float d5 = a5 - b5; s = __builtin_fmaf(d5, d5, s);
  return s;
}

// Semantics (A): op-by-op numpy/jnp rounding for the neighbor phase.
__device__ __forceinline__ float dist2_seq(
    float a0, float a1, float a2, float a3, float a4, float a5,
    float b0, float b1, float b2, float b3, float b4, float b5) {
#pragma clang fp contract(off)
  float d0 = a0 - b0; float s = d0 * d0;
  float d1 = a1 - b1; s = s + d1 * d1;
  float d2 = a2 - b2; s = s + d2 * d2;
  float d3 = a3 - b3; s = s + d3 * d3;
  float d4 = a4 - b4; s = s + d4 * d4;
  float d5 = a5 - b5; s = s + d5 * d5;
  return s;
}

// ---------------------------------------------------------------------------
// Kernel 1: FPS, KS=4 blocks per cloud, ZERO-barrier pick loop.
//
// R3 POST-MORTEM: all-wave polling (128 polling waves, 64 lanes each) of the
// MALL-coherent slots starved the publishers' stores on the same cache lines
// (FETCH_SIZE 4.6 -> 35 GB) — contention feedback doubled the per-pick
// latency. R2 POST-MORTEM: the 2-level reduce paid two barriers + a serial
// wave0 scan (~2000 cy) on top of the MALL round trip.
//
// R4 STRUCTURE (one MALL RT, minimal agents, no barriers):
//   - each wave publishes its OWN wave-winner key to slots[par][cloud][gw]
//     (fire-and-forget store; skips intra-block reduce entirely);
//   - ONE polling wave per block (wave 0): lane L polls slot L&31 until its
//     tag arrives, then 6-step u64 shfl umax -> cloud winner;
//   - wave 0 lane 0 posts {tag|g} to an LDS word; sibling waves spin on it
//     (monotone u32 compare, ~50 cy) instead of a barrier.
//
//   key = [57:46]=tag(k+1) | [45:14]=float_bits(bestv) | [13:0]=16383-idx
//
// umax over keys == argmax with tie -> smallest index (bestv >= 0, finite, so
// float bits are order-preserving; inverted idx makes max = min-index on
// ties). Associative/commutative with unique index bits -> reduction order
// irrelevant -> picks bit-identical to the single-block sweep.
//
// Lap-safety (parity double-buffer, global slots AND the LDS word):
// a same-parity rewrite happens at k+2 and requires the writer to have
// passed its iteration-(k+1) wait; wave0 agents are sequential (they finish
// their iteration-k poll before publishing tag k+2), and non-polling waves
// pass their iteration-(k+1) LDS spin only after their block's wave0
// completed poll k+1, which required THIS wave's tag-(k+2) publish, which
// follows its iteration-k LDS spin. Publish-before-poll => no deadlock.
// All communicated state lives in single words => relaxed is sufficient.
// ---------------------------------------------------------------------------
__global__
__attribute__((amdgpu_flat_work_group_size(FPS_T, FPS_T)))
__attribute__((amdgpu_waves_per_eu(2, 2)))
void fps_kernel(
    const float* __restrict__ x, const float* __restrict__ pos,
    float* __restrict__ out, unsigned long long* __restrict__ slots) {
  __shared__ unsigned s_res[2];  // {tag<<14 | g} per parity

  const int b = blockIdx.x & (BATCH - 1);  // cloud
  const int sblk = blockIdx.x >> 2;        // sub-block within cloud (0..KS-1)
  const int t = threadIdx.x;
  const int w = t >> 6;                    // wave within block
  const int lane = t & 63;
  const int gw = sblk * WPB + w;           // wave id within cloud (0..NW-1)

  const float* xb = x + (size_t)b * NPTS * 3;
  const float* pb = pos + (size_t)b * NPTS * 3;

  float* out_pos = out + (size_t)BATCH * M * 3;              // second output
  int* idx_stash = (int*)(out + (size_t)2 * BATCH * M * 3);  // batch region

  const int pbase = sblk * PPB;  // this block's point range

  if (t == 0) {
    s_res[0] = 0u;
    s_res[1] = 0u;
  }

  // My 8 points' 6-D coords + mind, all registers (56 f32, no AGPR straddle).
  float c0[PPT], c1[PPT], c2[PPT], c3[PPT], c4[PPT], c5[PPT], mind[PPT];
#pragma unroll
  for (int j = 0; j < PPT; ++j) {
    const int p = pbase + j * FPS_T + t;
    c0[j] = xb[3 * p + 0];
    c1[j] = xb[3 * p + 1];
    c2[j] = xb[3 * p + 2];
    c3[j] = pb[3 * p + 0];
    c4[j] = pb[3 * p + 1];
    c5[j] = pb[3 * p + 2];
    mind[j] = INFINITY;  // minimum(inf, d) == d on the first pick
  }
  __syncthreads();  // one-time: s_res init visible before the loop

  int g = 0;  // current pick (uniform; scalarized via readfirstlane)
  for (int k = 0; k < M; ++k) {
    // g is wave-uniform -> scalar center loads (L2-resident).
    const float fx0 = xb[3 * g + 0];
    const float fx1 = xb[3 * g + 1];
    const float fx2 = xb[3 * g + 2];
    const float fx3 = pb[3 * g + 0];
    const float fx4 = pb[3 * g + 1];
    const float fx5 = pb[3 * g + 2];

    if (sblk == 0 && t == 0) {
      idx_stash[b * M + k] = g;                    // for kernel 2
      out_pos[(size_t)(b * M + k) * 3 + 0] = fx3;  // pos[idx_g] (exact copy)
      out_pos[(size_t)(b * M + k) * 3 + 1] = fx4;
      out_pos[(size_t)(b * M + k) * 3 + 2] = fx5;
    }
    if (k == M - 1) break;  // last pick needs no further update/argmax

    // Min-update + per-thread (max, first-j). j ascending => p ascending, so
    // strict > keeps the earliest original index within this thread.
    float bestv = -1.0f;  // minds are >= 0, finite after the first update
    int bestj = 0;
#pragma unroll
    for (int j = 0; j < PPT; ++j) {
      const float d2 = dist2_fma(c0[j], c1[j], c2[j], c3[j], c4[j], c5[j],
                                 fx0, fx1, fx2, fx3, fx4, fx5);
      const float nm = fminf(mind[j], d2);  // == jnp.minimum (no NaNs)
      mind[j] = nm;
      if (nm > bestv) {
        bestv = nm;
        bestj = j;
      }
    }
    const int besti = pbase + bestj * FPS_T + t;  // cloud-local point index

    // Pack to a tag-less key and wave-reduce as u64 umax (3 VALU/step).
    unsigned long long kk =
        ((unsigned long long)__float_as_uint(bestv) << 14) |
        (unsigned long long)(unsigned)(16383 - besti);
#pragma unroll
    for (int off = 32; off > 0; off >>= 1) {
      const unsigned long long o = __shfl_xor(kk, off, 64);
      if (o > kk) kk = o;
    }

    // Publish this wave's winner (fire-and-forget; tag added here).
    unsigned long long* set =
        slots + (size_t)(((k & 1) * BATCH + b) * NW);
    if (lane == 0) {
      const unsigned long long key =
          ((unsigned long long)(unsigned)(k + 1) << 46) | kk;
      __hip_atomic_store(&set[gw], key, __ATOMIC_RELAXED,
                         __HIP_MEMORY_SCOPE_AGENT);
    }

    if (w == 0) {
      // The block's single polling wave: lane L polls slot L&31.
      const unsigned long long want = (unsigned long long)(unsigned)(k + 1);
      unsigned long long got;
      {
        unsigned long long* sp = &set[lane & (NW - 1)];
        do {
          got = __hip_atomic_load(sp, __ATOMIC_RELAXED,
                                  __HIP_MEMORY_SCOPE_AGENT);
        } while ((got >> 46) < want);
      }
#pragma unroll
      for (int off = 32; off > 0; off >>= 1) {
        const unsigned long long o = __shfl_xor(got, off, 64);
        if (o > got) got = o;
      }
      if (lane == 0) {
        const unsigned word = ((unsigned)(k + 1) << 14) |
                              (unsigned)(16383u - (unsigned)(got & 0x3FFFull));
        __hip_atomic_store(&s_res[k & 1], word, __ATOMIC_RELAXED,
                           __HIP_MEMORY_SCOPE_WORKGROUP);
      }
    }

    // All waves (incl. wave 0) pick up the result from the LDS word.
    // word = tag<<14 | g is monotone in tag and g < 2^14, so a single
    // unsigned compare implements "tag >= k+1" (proof above: exit sees
    // exactly tag k+1).
    {
      const unsigned wantw = (unsigned)(k + 1) << 14;
      unsigned word;
      do {
        word = __hip_atomic_load(&s_res[k & 1], __ATOMIC_RELAXED,
                                 __HIP_MEMORY_SCOPE_WORKGROUP);
      } while (word < wantw);
      g = __builtin_amdgcn_readfirstlane((int)(word & 0x3FFFu));
    }
  }
}

// ---------------------------------------------------------------------------
// Kernel 2: radius-neighbor capped mean (passed R3, ~0.15 ms). Unchanged.
// ---------------------------------------------------------------------------
#define K2_T 256
__global__ __launch_bounds__(K2_T, 4) void nbr_kernel(
    const float* __restrict__ x, const float* __restrict__ pos,
    float* __restrict__ out) {
  const int lane = threadIdx.x & 63;
  const int w = threadIdx.x >> 6;
  const int cbase = blockIdx.x * 16 + w * 4;  // 4 centers per wave

  const int* idx_stash = (const int*)(out + (size_t)2 * BATCH * M * 3);
  float* out_x = out;
  float* out_batch = out + (size_t)2 * BATCH * M * 3;

  const int b = cbase / M;  // all 16 centers of a block share a cloud
  const float* xb = x + (size_t)b * NPTS * 3;
  const float* pb = pos + (size_t)b * NPTS * 3;

  float cc0[4], cc1[4], cc2[4], cc3[4], cc4[4], cc5[4];
#pragma unroll
  for (int i = 0; i < 4; ++i) {
    const int c = idx_stash[cbase + i];  // local index within cloud
    cc0[i] = xb[3 * c + 0];
    cc1[i] = xb[3 * c + 1];
    cc2[i] = xb[3 * c + 2];
    cc3[i] = pb[3 * c + 0];
    cc4[i] = pb[3 * c + 1];
    cc5[i] = pb[3 * c + 2];
  }

  float s0[4] = {0, 0, 0, 0}, s1[4] = {0, 0, 0, 0}, s2[4] = {0, 0, 0, 0};
  int cnt[4] = {0, 0, 0, 0};

  for (int p = lane; p < NPTS; p += 64) {
    const float x0 = xb[3 * p + 0];
    const float x1 = xb[3 * p + 1];
    const float x2 = xb[3 * p + 2];
    const float q0 = pb[3 * p + 0];
    const float q1 = pb[3 * p + 1];
    const float q2 = pb[3 * p + 2];
#pragma unroll
    for (int i = 0; i < 4; ++i) {
      const float d2 = dist2_seq(cc0[i], cc1[i], cc2[i], cc3[i], cc4[i],
                                 cc5[i], x0, x1, x2, q0, q1, q2);
      if (d2 <= R2F) {
        cnt[i] += 1;
        s0[i] += x0;
        s1[i] += x1;
        s2[i] += x2;
      }
    }
  }

#pragma unroll
  for (int i = 0; i < 4; ++i) {
#pragma unroll
    for (int off = 32; off > 0; off >>= 1) {
      s0[i] += __shfl_xor(s0[i], off, 64);
      s1[i] += __shfl_xor(s1[i], off, 64);
      s2[i] += __shfl_xor(s2[i], off, 64);
      cnt[i] += __shfl_xor(cnt[i], off, 64);
    }
  }

#pragma unroll
  for (int i = 0; i < 4; ++i) {
    const int total = cnt[i];
    float m0, m1, m2;
    if (total <= MAX_NB) {
      const float denom = (float)total;  // >= 1 (self is always in range)
      m0 = s0[i] / denom;
      m1 = s1[i] / denom;
      m2 = s2[i] / denom;
    } else {
      // Exact first-64-by-index fallback (wave-uniform branch, rare).
      const int base = lane * (NPTS / 64);
      int lc = 0;
      for (int p = base; p < base + NPTS / 64; ++p) {
        const float d2 =
            dist2_seq(cc0[i], cc1[i], cc2[i], cc3[i], cc4[i], cc5[i],
                      xb[3 * p + 0], xb[3 * p + 1], xb[3 * p + 2],
                      pb[3 * p + 0], pb[3 * p + 1], pb[3 * p + 2]);
        if (d2 <= R2F) lc += 1;
      }
      int pre = 0;
      for (int l = 0; l < 64; ++l) {
        const int c = __shfl(lc, l, 64);
        if (l < lane) pre += c;
      }
      float t0 = 0, t1 = 0, t2 = 0;
      int r = pre;
      for (int p = base; p < base + NPTS / 64; ++p) {
        const float x0 = xb[3 * p + 0], x1 = xb[3 * p + 1],
                    x2 = xb[3 * p + 2];
        const float d2 =
            dist2_seq(cc0[i], cc1[i], cc2[i], cc3[i], cc4[i], cc5[i], x0, x1,
                      x2, pb[3 * p + 0], pb[3 * p + 1], pb[3 * p + 2]);
        if (d2 <= R2F) {
          if (r < MAX_NB) {
            t0 += x0;
            t1 += x1;
            t2 += x2;
          }
          r += 1;
        }
      }
#pragma unroll
      for (int off = 32; off > 0; off >>= 1) {
        t0 += __shfl_xor(t0, off, 64);
        t1 += __shfl_xor(t1, off, 64);
        t2 += __shfl_xor(t2, off, 64);
      }
      m0 = t0 / 64.0f;
      m1 = t1 / 64.0f;
      m2 = t2 / 64.0f;
    }
    if (lane == i) {
      const int gc = cbase + i;
      out_x[(size_t)gc * 3 + 0] = m0;
      out_x[(size_t)gc * 3 + 1] = m1;
      out_x[(size_t)gc * 3 + 2] = m2;
      out_batch[gc] = (float)b;  // batch ids as float in the float32 buffer
    }
  }
}

extern "C" void kernel_launch(void* const* d_in, const int* in_sizes, int n_in,
                              void* d_out, int out_size, void* d_ws,
                              size_t ws_size, hipStream_t stream) {
  (void)in_sizes;
  (void)n_in;
  (void)out_size;
  const float* x = (const float*)d_in[0];
  const float* pos = (const float*)d_in[1];
  // d_in[2] (batch) is implied by the contiguous equal-size layout.
  float* out = (float*)d_out;

  // Cross-wave exchange slots, double-buffered by iteration parity:
  // [2][BATCH][NW] u64 = 2 KiB. Prefer the workspace; fall back to the head
  // of out_x (fully overwritten later by nbr_kernel; never read by fps).
  const size_t slot_bytes =
      (size_t)2 * BATCH * NW * sizeof(unsigned long long);
  unsigned long long* slots = (ws_size >= slot_bytes)
                                  ? (unsigned long long*)d_ws
                                  : (unsigned long long*)d_out;
  // Must clear every launch: stale tags from a previous run would satisfy
  // the tag-poll early and corrupt picks on graph replay.
  hipMemsetAsync(slots, 0, slot_bytes, stream);

  fps_kernel<<<BATCH * KS, FPS_T, 0, stream>>>(x, pos, out, slots);
  nbr_kernel<<<(BATCH * M) / 16, K2_T, 0, stream>>>(x, pos, out);
}

// Round 5
// 7668.495 us; speedup vs baseline: 2.3967x; 1.4379x over previous
//
#include <hip/hip_runtime.h>
#include <math.h>

// Problem constants (match reference file)
#define BATCH 4
#define NPTS 16384
#define M 4096          // centers per cloud = RATIO * NPTS
#define MAX_NB 64
#define R2F 0.0625f     // R*R = 0.25*0.25 (exactly representable)

// FPS split: KS blocks per cloud, each owning NPTS/KS points.
#define KS 4
#define FPS_T 512                 // threads per FPS block
#define WPB (FPS_T / 64)          // waves per block = 8
#define PPB (NPTS / KS)           // points per block = 4096
#define PPT (PPB / FPS_T)         // points per thread = 8
#define SLOT_STRIDE 32            // u64s per (parity,cloud) sector = 256 B

// ---------------------------------------------------------------------------
// Semantics (B): XLA-fused scan-body rounding (verified bit-exact earlier).
// ---------------------------------------------------------------------------
__device__ __forceinline__ float dist2_fma(
    float a0, float a1, float a2, float a3, float a4, float a5,
    float b0, float b1, float b2, float b3, float b4, float b5) {
  float d0 = a0 - b0;
  float s = __builtin_fmaf(d0, d0, 0.0f);
  float d1 = a1 - b1; s = __builtin_fmaf(d1, d1, s);
  float d2 = a2 - b2; s = __builtin_fmaf(d2, d2, s);
  float d3 = a3 - b3; s = __builtin_fmaf(d3, d3, s);
  float d4 = a4 - b4; s = __builtin_fmaf(d4, d4, s);
  float d5 = a5 - b5; s = __builtin_fmaf(d5, d5, s);
  return s;
}

// Semantics (A): op-by-op numpy/jnp rounding for the neighbor phase.
__device__ __forceinline__ float dist2_seq(
    float a0, float a1, float a2, float a3, float a4, float a5,
    float b0, float b1, float b2, float b3, float b4, float b5) {
#pragma clang fp contract(off)
  float d0 = a0 - b0; float s = d0 * d0;
  float d1 = a1 - b1; s = s + d1 * d1;
  float d2 = a2 - b2; s = s + d2 * d2;
  float d3 = a3 - b3; s = s + d3 * d3;
  float d4 = a4 - b4; s = s + d4 * d4;
  float d5 = a5 - b5; s = s + d5 * d5;
  return s;
}

// ---------------------------------------------------------------------------
// Kernel 1: FPS, KS=4 blocks per cloud; barrier-free; MINIMAL exchange.
//
// Per-round latency ledger across rounds (cy/pick): R0=5430, R2=5780,
// R3=11000, R4=6150. The MALL round trip scales with publisher/poll-lane
// concurrency (R2: 4 pub + 16 poll lanes -> RT~2500; R4: 32 pub + 256 poll
// lanes -> RT~4300; R3: 8192 poll lanes -> ~9000). R5 keeps R2's minimal
// exchange (4 publishers per cloud, lanes 0-3 of one wave per block polling
// ONE 32-byte group) and replaces R2's ~2000-cy intra-block tail (2 barriers
// + serial wave0 scan) with tagged-LDS-slot combine (~450 cy):
//
//   1. every wave:   lane0 ds_write {tag|key} -> s_wk[par][w]
//   2. wave 0:       spin-read 8 LDS slots (monotone tag), 3-step shfl umax,
//                    lane0 stores block key -> gsector[par][cloud][sblk]
//   3. wave 0:       lanes 0-3 poll the 4 block keys, 2-step shfl umax,
//                    lane0 posts {tag<<14|g} -> s_res[par]
//   4. all waves:    spin s_res[par] (one ds_read, monotone u32 compare)
//
//   key = [57:46]=tag(k+1) | [45:14]=float_bits(bestv) | [13:0]=16383-idx
//
// umax over keys == argmax with tie -> smallest index (bestv >= 0 finite so
// float bits are order-preserving; inverted idx makes max = min-index on
// ties). Keys are distinct (idx bits) and max is associative/commutative ->
// reduction order irrelevant -> picks bit-identical to the reference scan.
//
// Lap-safety (parity double-buffer on s_wk, gsector, s_res): a same-parity
// rewrite happens at k+2 and requires the writer to have passed its
// iteration-(k+1) wait, which transitively requires every reader to have
// finished its iteration-k wait on that very location (publish-before-poll
// at every stage). So an exiting spin sees exactly tag k+1. No deadlock:
// each agent publishes everything it owes before its first wait of the
// round. All communicated state lives in single 64-/32-bit words ->
// relaxed atomics suffice; each (parity,cloud) global set is padded to its
// own 256-B sector to kill cross-round/cross-cloud false sharing.
// ---------------------------------------------------------------------------
__global__
__attribute__((amdgpu_flat_work_group_size(FPS_T, FPS_T)))
__attribute__((amdgpu_waves_per_eu(2, 2)))
void fps_kernel(
    const float* __restrict__ x, const float* __restrict__ pos,
    float* __restrict__ out, unsigned long long* __restrict__ slots) {
  __shared__ unsigned long long s_wk[2][WPB];  // tagged wave-winner keys
  __shared__ unsigned s_res[2];                // {tag<<14 | g} per parity

  const int b = blockIdx.x & (BATCH - 1);  // cloud
  const int sblk = blockIdx.x >> 2;        // sub-block within cloud (0..KS-1)
  const int t = threadIdx.x;
  const int w = t >> 6;                    // wave within block
  const int lane = t & 63;

  const float* xb = x + (size_t)b * NPTS * 3;
  const float* pb = pos + (size_t)b * NPTS * 3;

  float* out_pos = out + (size_t)BATCH * M * 3;              // second output
  int* idx_stash = (int*)(out + (size_t)2 * BATCH * M * 3);  // batch region

  const int pbase = sblk * PPB;  // this block's point range

  if (t < 2 * WPB) s_wk[t >> 3][t & 7] = 0ull;
  if (t == 2 * WPB) { s_res[0] = 0u; s_res[1] = 0u; }

  // My 8 points' 6-D coords + mind, all registers (56 f32, no AGPR straddle).
  float c0[PPT], c1[PPT], c2[PPT], c3[PPT], c4[PPT], c5[PPT], mind[PPT];
#pragma unroll
  for (int j = 0; j < PPT; ++j) {
    const int p = pbase + j * FPS_T + t;
    c0[j] = xb[3 * p + 0];
    c1[j] = xb[3 * p + 1];
    c2[j] = xb[3 * p + 2];
    c3[j] = pb[3 * p + 0];
    c4[j] = pb[3 * p + 1];
    c5[j] = pb[3 * p + 2];
    mind[j] = INFINITY;  // minimum(inf, d) == d on the first pick
  }
  __syncthreads();  // one-time: LDS init visible before the loop

  int g = 0;  // current pick (uniform; scalarized via readfirstlane)
  for (int k = 0; k < M; ++k) {
    // g is wave-uniform -> scalar center loads (L2-resident).
    const float fx0 = xb[3 * g + 0];
    const float fx1 = xb[3 * g + 1];
    const float fx2 = xb[3 * g + 2];
    const float fx3 = pb[3 * g + 0];
    const float fx4 = pb[3 * g + 1];
    const float fx5 = pb[3 * g + 2];

    if (sblk == 0 && t == 0) {
      idx_stash[b * M + k] = g;                    // for kernel 2
      out_pos[(size_t)(b * M + k) * 3 + 0] = fx3;  // pos[idx_g] (exact copy)
      out_pos[(size_t)(b * M + k) * 3 + 1] = fx4;
      out_pos[(size_t)(b * M + k) * 3 + 2] = fx5;
    }
    if (k == M - 1) break;  // last pick needs no further update/argmax

    // Min-update + per-thread (max, first-j). j ascending => p ascending, so
    // strict > keeps the earliest original index within this thread.
    float bestv = -1.0f;  // minds are >= 0, finite after the first update
    int bestj = 0;
#pragma unroll
    for (int j = 0; j < PPT; ++j) {
      const float d2 = dist2_fma(c0[j], c1[j], c2[j], c3[j], c4[j], c5[j],
                                 fx0, fx1, fx2, fx3, fx4, fx5);
      const float nm = fminf(mind[j], d2);  // == jnp.minimum (no NaNs)
      mind[j] = nm;
      if (nm > bestv) {
        bestv = nm;
        bestj = j;
      }
    }
    const int besti = pbase + bestj * FPS_T + t;  // cloud-local point index

    // Pack and wave-reduce as u64 umax.
    unsigned long long kk =
        ((unsigned long long)__float_as_uint(bestv) << 14) |
        (unsigned long long)(unsigned)(16383 - besti);
#pragma unroll
    for (int off = 32; off > 0; off >>= 1) {
      const unsigned long long o = __shfl_xor(kk, off, 64);
      if (o > kk) kk = o;
    }

    const int par = k & 1;
    const unsigned long long want = (unsigned long long)(unsigned)(k + 1);
    const unsigned long long tagged = (want << 46) | kk;

    // Stage 1: every wave posts its winner to the tagged LDS slot.
    if (lane == 0) {
      __hip_atomic_store(&s_wk[par][w], tagged, __ATOMIC_RELAXED,
                         __HIP_MEMORY_SCOPE_WORKGROUP);
    }

    if (w == 0) {
      // Stage 2: combine the 8 wave keys (lane L spins slot L&7; LDS
      // broadcast makes the 8x coverage free), 3-step shfl umax.
      unsigned long long got;
      do {
        got = __hip_atomic_load(&s_wk[par][lane & (WPB - 1)],
                                __ATOMIC_RELAXED,
                                __HIP_MEMORY_SCOPE_WORKGROUP);
      } while ((got >> 46) < want);
#pragma unroll
      for (int off = 1; off < WPB; off <<= 1) {
        const unsigned long long o = __shfl_xor(got, off, 64);
        if (o > got) got = o;
      }
      // Publish block winner to this (parity,cloud) 256-B sector.
      unsigned long long* sector =
          slots + (size_t)(par * BATCH + b) * SLOT_STRIDE;
      if (lane == 0) {
        __hip_atomic_store(&sector[sblk], got, __ATOMIC_RELAXED,
                           __HIP_MEMORY_SCOPE_AGENT);
      }
      // Stage 3: lanes 0-3 poll the 4 block keys (one 32-B group).
      unsigned long long cw = got;
      if (lane < KS) {
        unsigned long long o;
        do {
          o = __hip_atomic_load(&sector[lane], __ATOMIC_RELAXED,
                                __HIP_MEMORY_SCOPE_AGENT);
        } while ((o >> 46) < want);
        if (o > cw) cw = o;
      }
#pragma unroll
      for (int off = 1; off < KS; off <<= 1) {
        const unsigned long long o = __shfl_xor(cw, off, 64);
        if (o > cw) cw = o;
      }
      if (lane == 0) {
        const unsigned word = ((unsigned)(k + 1) << 14) |
                              (unsigned)(16383u - (unsigned)(cw & 0x3FFFull));
        __hip_atomic_store(&s_res[par], word, __ATOMIC_RELAXED,
                           __HIP_MEMORY_SCOPE_WORKGROUP);
      }
    }

    // Stage 4: all waves pick up the result. word = tag<<14 | g is monotone
    // in tag and g < 2^14, so one unsigned compare implements "tag >= k+1"
    // (lap-proof above: exit sees exactly tag k+1).
    {
      const unsigned wantw = (unsigned)(k + 1) << 14;
      unsigned word;
      do {
        word = __hip_atomic_load(&s_res[par], __ATOMIC_RELAXED,
                                 __HIP_MEMORY_SCOPE_WORKGROUP);
      } while (word < wantw);
      g = __builtin_amdgcn_readfirstlane((int)(word & 0x3FFFu));
    }
  }
}

// ---------------------------------------------------------------------------
// Kernel 2: radius-neighbor capped mean (verified, ~0.15 ms). Unchanged.
// ---------------------------------------------------------------------------
#define K2_T 256
__global__ __launch_bounds__(K2_T, 4) void nbr_kernel(
    const float* __restrict__ x, const float* __restrict__ pos,
    float* __restrict__ out) {
  const int lane = threadIdx.x & 63;
  const int w = threadIdx.x >> 6;
  const int cbase = blockIdx.x * 16 + w * 4;  // 4 centers per wave

  const int* idx_stash = (const int*)(out + (size_t)2 * BATCH * M * 3);
  float* out_x = out;
  float* out_batch = out + (size_t)2 * BATCH * M * 3;

  const int b = cbase / M;  // all 16 centers of a block share a cloud
  const float* xb = x + (size_t)b * NPTS * 3;
  const float* pb = pos + (size_t)b * NPTS * 3;

  float cc0[4], cc1[4], cc2[4], cc3[4], cc4[4], cc5[4];
#pragma unroll
  for (int i = 0; i < 4; ++i) {
    const int c = idx_stash[cbase + i];  // local index within cloud
    cc0[i] = xb[3 * c + 0];
    cc1[i] = xb[3 * c + 1];
    cc2[i] = xb[3 * c + 2];
    cc3[i] = pb[3 * c + 0];
    cc4[i] = pb[3 * c + 1];
    cc5[i] = pb[3 * c + 2];
  }

  float s0[4] = {0, 0, 0, 0}, s1[4] = {0, 0, 0, 0}, s2[4] = {0, 0, 0, 0};
  int cnt[4] = {0, 0, 0, 0};

  for (int p = lane; p < NPTS; p += 64) {
    const float x0 = xb[3 * p + 0];
    const float x1 = xb[3 * p + 1];
    const float x2 = xb[3 * p + 2];
    const float q0 = pb[3 * p + 0];
    const float q1 = pb[3 * p + 1];
    const float q2 = pb[3 * p + 2];
#pragma unroll
    for (int i = 0; i < 4; ++i) {
      const float d2 = dist2_seq(cc0[i], cc1[i], cc2[i], cc3[i], cc4[i],
                                 cc5[i], x0, x1, x2, q0, q1, q2);
      if (d2 <= R2F) {
        cnt[i] += 1;
        s0[i] += x0;
        s1[i] += x1;
        s2[i] += x2;
      }
    }
  }

#pragma unroll
  for (int i = 0; i < 4; ++i) {
#pragma unroll
    for (int off = 32; off > 0; off >>= 1) {
      s0[i] += __shfl_xor(s0[i], off, 64);
      s1[i] += __shfl_xor(s1[i], off, 64);
      s2[i] += __shfl_xor(s2[i], off, 64);
      cnt[i] += __shfl_xor(cnt[i], off, 64);
    }
  }

#pragma unroll
  for (int i = 0; i < 4; ++i) {
    const int total = cnt[i];
    float m0, m1, m2;
    if (total <= MAX_NB) {
      const float denom = (float)total;  // >= 1 (self is always in range)
      m0 = s0[i] / denom;
      m1 = s1[i] / denom;
      m2 = s2[i] / denom;
    } else {
      // Exact first-64-by-index fallback (wave-uniform branch, rare).
      const int base = lane * (NPTS / 64);
      int lc = 0;
      for (int p = base; p < base + NPTS / 64; ++p) {
        const float d2 =
            dist2_seq(cc0[i], cc1[i], cc2[i], cc3[i], cc4[i], cc5[i],
                      xb[3 * p + 0], xb[3 * p + 1], xb[3 * p + 2],
                      pb[3 * p + 0], pb[3 * p + 1], pb[3 * p + 2]);
        if (d2 <= R2F) lc += 1;
      }
      int pre = 0;
      for (int l = 0; l < 64; ++l) {
        const int c = __shfl(lc, l, 64);
        if (l < lane) pre += c;
      }
      float t0 = 0, t1 = 0, t2 = 0;
      int r = pre;
      for (int p = base; p < base + NPTS / 64; ++p) {
        const float x0 = xb[3 * p + 0], x1 = xb[3 * p + 1],
                    x2 = xb[3 * p + 2];
        const float d2 =
            dist2_seq(cc0[i], cc1[i], cc2[i], cc3[i], cc4[i], cc5[i], x0, x1,
                      x2, pb[3 * p + 0], pb[3 * p + 1], pb[3 * p + 2]);
        if (d2 <= R2F) {
          if (r < MAX_NB) {
            t0 += x0;
            t1 += x1;
            t2 += x2;
          }
          r += 1;
        }
      }
#pragma unroll
      for (int off = 32; off > 0; off >>= 1) {
        t0 += __shfl_xor(t0, off, 64);
        t1 += __shfl_xor(t1, off, 64);
        t2 += __shfl_xor(t2, off, 64);
      }
      m0 = t0 / 64.0f;
      m1 = t1 / 64.0f;
      m2 = t2 / 64.0f;
    }
    if (lane == i) {
      const int gc = cbase + i;
      out_x[(size_t)gc * 3 + 0] = m0;
      out_x[(size_t)gc * 3 + 1] = m1;
      out_x[(size_t)gc * 3 + 2] = m2;
      out_batch[gc] = (float)b;  // batch ids as float in the float32 buffer
    }
  }
}

extern "C" void kernel_launch(void* const* d_in, const int* in_sizes, int n_in,
                              void* d_out, int out_size, void* d_ws,
                              size_t ws_size, hipStream_t stream) {
  (void)in_sizes;
  (void)n_in;
  (void)out_size;
  const float* x = (const float*)d_in[0];
  const float* pos = (const float*)d_in[1];
  // d_in[2] (batch) is implied by the contiguous equal-size layout.
  float* out = (float*)d_out;

  // Cross-block exchange sectors: [2 parities][BATCH clouds] x 256 B = 2 KiB.
  // Prefer the workspace; fall back to the head of out_x (fully overwritten
  // later by nbr_kernel; never read by fps).
  const size_t slot_bytes =
      (size_t)2 * BATCH * SLOT_STRIDE * sizeof(unsigned long long);
  unsigned long long* slots = (ws_size >= slot_bytes)
                                  ? (unsigned long long*)d_ws
                                  : (unsigned long long*)d_out;
  // Must clear every launch: stale tags from a previous run would satisfy
  // the tag-poll early and corrupt picks on graph replay.
  hipMemsetAsync(slots, 0, slot_bytes, stream);

  fps_kernel<<<BATCH * KS, FPS_T, 0, stream>>>(x, pos, out, slots);
  nbr_kernel<<<(BATCH * M) / 16, K2_T, 0, stream>>>(x, pos, out);
}